// Round 7
// baseline (152.922 us; speedup 1.0000x reference)
//
#include <hip/hip_runtime.h>
#include <hip/hip_bf16.h>
#include <cstdint>
#include <cstddef>

// Problem constants (fixed by the reference: anchor/positive [4096,512] f32, labels [4096] i32)
constexpr int BN = 4096;   // batch
constexpr int DN = 512;    // feature dim
constexpr int NT = BN / 128;              // 32 tiles per dim
constexpr int NBLK = NT * (NT + 1) / 2;   // 528 triangular tile-pairs
constexpr float MARGIN = 0.2f;
constexpr uint32_t INF_U = 0x7f800000u;   // +inf bits; positive-float order == uint order

typedef __attribute__((ext_vector_type(8))) short short8;     // 8 bf16 = 4 VGPRs (MFMA A/B frag)
typedef __attribute__((ext_vector_type(4))) float float4v;    // MFMA C/D frag

// ---------------------------------------------------------------------------
// Kernel 1: per-row stats + bf16 cast of anchor + init of min arrays + counter.
// One wave per row (4 rows / 256-thread block). Lane l owns elems [8l, 8l+8).
// meta[row] = {||a||^2, d_ap(squared), d_ap^2, label-bits}  (one b128 load later)
// ---------------------------------------------------------------------------
__global__ __launch_bounds__(256) void prep_kernel(
    const float* __restrict__ anchor,
    const float* __restrict__ positive,
    const int* __restrict__ labels,
    uint16_t* __restrict__ Abf,        // [BN][DN] bf16 bits
    float4* __restrict__ meta,         // [BN]
    uint32_t* __restrict__ min_all,    // [BN] +inf-initialized (min over d2)
    uint32_t* __restrict__ min_larger, // [BN] +inf-initialized (min over d2)
    uint32_t* __restrict__ done_count) // single counter, zeroed here
{
    const int tid  = threadIdx.x;
    const int wave = tid >> 6;
    const int lane = tid & 63;
    const int row  = blockIdx.x * 4 + wave;

    if (blockIdx.x == 0 && tid == 0) *done_count = 0;

    const float4* arow = (const float4*)(anchor   + (size_t)row * DN);
    const float4* prow = (const float4*)(positive + (size_t)row * DN);

    float4 av0 = arow[lane * 2 + 0], av1 = arow[lane * 2 + 1];
    float4 pv0 = prow[lane * 2 + 0], pv1 = prow[lane * 2 + 1];

    float a[8] = {av0.x, av0.y, av0.z, av0.w, av1.x, av1.y, av1.z, av1.w};
    float p[8] = {pv0.x, pv0.y, pv0.z, pv0.w, pv1.x, pv1.y, pv1.z, pv1.w};

    float s = 0.f, d = 0.f;
    union { uint16_t u[8]; uint4 v; } pk;
    #pragma unroll
    for (int i = 0; i < 8; ++i) {
        s += a[i] * a[i];
        float dx = a[i] - p[i];
        d += dx * dx;
        uint32_t ub = __float_as_uint(a[i]);               // RNE f32 -> bf16
        pk.u[i] = (uint16_t)((ub + 0x7fffu + ((ub >> 16) & 1u)) >> 16);
    }

    ((uint4*)(Abf + (size_t)row * DN))[lane] = pk.v;       // 16B coalesced store

    #pragma unroll
    for (int off = 32; off; off >>= 1) {
        s += __shfl_xor(s, off);
        d += __shfl_xor(d, off);
    }
    if (lane == 0) {
        meta[row] = (float4){s, d, d * d, __uint_as_float((uint32_t)labels[row])};
        min_all[row]    = INF_U;
        min_larger[row] = INF_U;
    }
}

// ---------------------------------------------------------------------------
// Kernel 2: upper-triangular 128x128 tiles of S = A·A^T (bf16 MFMA 16x16x32).
// R4 structure (BK=64, XOR-8 swizzle, 32 KB LDS, 3 blocks/CU — best measured,
// 42 µs) + register double-buffer: prologue-load tile 0; per iter
// [barrier -> ds_write(kt) -> barrier -> ISSUE LOADS kt+1 -> ds_read+MFMA kt].
// Loads for kt+1 are in flight during compute of kt, so per-iter exposed L3
// latency (~800 cyc — Abf is spread over all 8 XCD L2s, reads go to Infinity
// Cache) collapses to ~0. R2 tried this and spilled (WRITE_SIZE 96 MB);
// launch_bounds(256,3) caps the allocator at ~170 unified regs, demand ~160.
// TRIPWIRE: WRITE_SIZE must stay ~5 MB; a jump means spills, result void.
// [R6: BK=128 regressed — 64.5 KB LDS -> 2 blocks/CU -> 16-block second-round
// tail, occupancy 10%. R5: frag-direct-from-global = 16-segment gathers, 71 µs.]
// Epilogue: squared-distance dual-side masked mins via uint atomicMin.
// Last block (device counter) folds in the finalize: select, sqrt, hinge, mean.
// ---------------------------------------------------------------------------
__global__ __launch_bounds__(256, 3) void gram_kernel(
    const uint16_t* __restrict__ Abf,
    const float4* __restrict__ meta,
    uint32_t* __restrict__ min_all,
    uint32_t* __restrict__ min_larger,
    uint32_t* __restrict__ done_count,
    float* __restrict__ out)
{
    __shared__ uint16_t Abuf[128 * 64];   // 16 KB, row stride 64 elem = 128 B = 32 banks
    __shared__ uint16_t Bbuf[128 * 64];   // 16 KB

    // triangular decode: blockIdx.x -> (bi, bj) with bi <= bj
    int t = blockIdx.x, bi = 0, rem = NT;
    while (t >= rem) { t -= rem; ++bi; --rem; }
    const int bj = bi + t;
    const bool offdiag = (bi != bj);
    const int rowBase = bi * 128;
    const int colBase = bj * 128;

    const int tid  = threadIdx.x;
    const int wave = tid >> 6;
    const int lane = tid & 63;
    const int wi   = wave >> 1;       // wave row in 2x2 grid
    const int wj   = wave & 1;        // wave col
    const int quad = lane >> 4;
    const int l15  = lane & 15;

    // Staging map: tile = 128 rows x 8 chunks of 16B = 1024 chunks; thread
    // handles l = tid + i*256 (i=0..3): row sr=l>>3, global chunk sc=l&7,
    // LDS slot sp = sc ^ (sr&7)  (XOR-8 swizzle; 0 conflicts measured R2-R6).
    int sr[4], sc[4], sp[4];
    #pragma unroll
    for (int i = 0; i < 4; ++i) {
        int l = tid + i * 256;
        sr[i] = l >> 3; sc[i] = l & 7; sp[i] = sc[i] ^ (sr[i] & 7);
    }

    uint4 aS[4], bS[4];                  // staging double-buffer (32 VGPRs)
    auto prefetch = [&](int k0) {
        #pragma unroll
        for (int i = 0; i < 4; ++i) {
            aS[i] = *(const uint4*)(Abf + (size_t)(rowBase + sr[i]) * DN + k0 + sc[i] * 8);
            bS[i] = *(const uint4*)(Abf + (size_t)(colBase + sr[i]) * DN + k0 + sc[i] * 8);
        }
    };
    prefetch(0);

    float4v acc[4][4];
    #pragma unroll
    for (int i = 0; i < 4; ++i)
        #pragma unroll
        for (int j = 0; j < 4; ++j)
            acc[i][j] = (float4v){0.f, 0.f, 0.f, 0.f};

    for (int kt = 0; kt < DN / 64; ++kt) {
        __syncthreads();              // readers of previous tile done
        #pragma unroll
        for (int i = 0; i < 4; ++i)
            *(uint4*)(Abuf + sr[i] * 64 + sp[i] * 8) = aS[i];
        #pragma unroll
        for (int i = 0; i < 4; ++i)
            *(uint4*)(Bbuf + sr[i] * 64 + sp[i] * 8) = bS[i];
        __syncthreads();              // LDS tiles visible
        if (kt < DN / 64 - 1) prefetch((kt + 1) * 64);   // in flight during compute

        #pragma unroll
        for (int kk = 0; kk < 2; ++kk) {
            short8 af[4], bfr[4];
            #pragma unroll
            for (int mi = 0; mi < 4; ++mi) {
                int r = wi * 64 + mi * 16 + l15;
                int p = (kk * 4 + quad) ^ (r & 7);
                af[mi] = *(const short8*)(Abuf + r * 64 + p * 8);
            }
            #pragma unroll
            for (int mj = 0; mj < 4; ++mj) {
                int r = wj * 64 + mj * 16 + l15;
                int p = (kk * 4 + quad) ^ (r & 7);
                bfr[mj] = *(const short8*)(Bbuf + r * 64 + p * 8);
            }
            #pragma unroll
            for (int mi = 0; mi < 4; ++mi)
                #pragma unroll
                for (int mj = 0; mj < 4; ++mj)
                    acc[mi][mj] = __builtin_amdgcn_mfma_f32_16x16x32_bf16(
                        af[mi], bfr[mj], acc[mi][mj], 0, 0, 0);
        }
    }

    // ---- epilogue: squared distances, dual-side masked mins ----
    const float INFF = __uint_as_float(INF_U);
    float4 mj_meta[4];
    #pragma unroll
    for (int mj = 0; mj < 4; ++mj)
        mj_meta[mj] = meta[colBase + wj * 64 + mj * 16 + l15];   // C/D col = lane&15

    float cAll[4], cLarger[4];
    #pragma unroll
    for (int mj = 0; mj < 4; ++mj) { cAll[mj] = INFF; cLarger[mj] = INFF; }

    #pragma unroll
    for (int mi = 0; mi < 4; ++mi) {
        #pragma unroll
        for (int r = 0; r < 4; ++r) {
            int row = rowBase + wi * 64 + mi * 16 + quad * 4 + r;  // C/D row = quad*4+reg
            float4 mim = meta[row];          // {sqn, dap, dap^2, label}
            uint32_t li = __float_as_uint(mim.w);
            float mAll = INFF, mLarger = INFF;
            #pragma unroll
            for (int mj = 0; mj < 4; ++mj) {
                float d2 = mim.x + mj_meta[mj].x - 2.0f * acc[mi][mj][r];
                d2 = d2 > 0.f ? d2 : 0.f;
                if (__float_as_uint(mj_meta[mj].w) != li) {
                    mAll = fminf(mAll, d2);
                    // reference: pd (euclidean) > d_ap (squared)  <=>  d2 > dap^2
                    if (d2 > mim.z) mLarger = fminf(mLarger, d2);
                    if (offdiag) {
                        cAll[mj] = fminf(cAll[mj], d2);
                        if (d2 > mj_meta[mj].z) cLarger[mj] = fminf(cLarger[mj], d2);
                    }
                }
            }
            // min across the 16 lanes of this quad (they share `row`, cover 64 cols)
            #pragma unroll
            for (int off = 1; off < 16; off <<= 1) {
                mAll    = fminf(mAll,    __shfl_xor(mAll, off));
                mLarger = fminf(mLarger, __shfl_xor(mLarger, off));
            }
            if (l15 == 0) {
                atomicMin(&min_all[row],    __float_as_uint(mAll));
                atomicMin(&min_larger[row], __float_as_uint(mLarger));
            }
        }
    }
    if (offdiag) {
        // col j = colBase + wj*64 + mj*16 + l15 is shared by the 4 quads
        #pragma unroll
        for (int mj = 0; mj < 4; ++mj) {
            float a0 = cAll[mj], l0 = cLarger[mj];
            a0 = fminf(a0, __shfl_xor(a0, 16)); l0 = fminf(l0, __shfl_xor(l0, 16));
            a0 = fminf(a0, __shfl_xor(a0, 32)); l0 = fminf(l0, __shfl_xor(l0, 32));
            if (quad == 0) {
                int col = colBase + wj * 64 + mj * 16 + l15;
                atomicMin(&min_all[col],    __float_as_uint(a0));
                atomicMin(&min_larger[col], __float_as_uint(l0));
            }
        }
    }

    // ---- last-block finalize: select, sqrt, hinge, mean ----
    __shared__ bool isLast;
    __syncthreads();                      // all this block's atomics issued
    if (tid == 0) {
        __threadfence();                  // make our mins visible device-wide
        isLast = (atomicAdd(done_count, 1u) == NBLK - 1);
    }
    __syncthreads();
    if (isLast) {
        __threadfence();                  // acquire: see all other blocks' mins
        float s = 0.f;
        for (int i = tid; i < BN; i += 256) {
            uint32_t mlu = __hip_atomic_load(&min_larger[i], __ATOMIC_RELAXED, __HIP_MEMORY_SCOPE_AGENT);
            uint32_t mau = __hip_atomic_load(&min_all[i],    __ATOMIC_RELAXED, __HIP_MEMORY_SCOPE_AGENT);
            float dan2 = (mlu != INF_U) ? __uint_as_float(mlu) : __uint_as_float(mau);
            float l = meta[i].y - sqrtf(dan2) + MARGIN;
            s += l > 0.f ? l : 0.f;
        }
        #pragma unroll
        for (int off = 32; off; off >>= 1) s += __shfl_xor(s, off);
        __shared__ float wsum[4];
        if ((tid & 63) == 0) wsum[tid >> 6] = s;
        __syncthreads();
        if (tid == 0) out[0] = (wsum[0] + wsum[1] + wsum[2] + wsum[3]) * (1.0f / BN);
    }
}

// ---------------------------------------------------------------------------
extern "C" void kernel_launch(void* const* d_in, const int* in_sizes, int n_in,
                              void* d_out, int out_size, void* d_ws, size_t ws_size,
                              hipStream_t stream) {
    const float* anchor   = (const float*)d_in[0];
    const float* positive = (const float*)d_in[1];
    const int*   labels   = (const int*)d_in[2];
    float* out = (float*)d_out;

    // Workspace layout (~4.4 MB)
    uint8_t* ws = (uint8_t*)d_ws;
    uint16_t* Abf        = (uint16_t*)ws;                          // 4 MB bf16 anchor
    float4*   meta       = (float4*)(ws + (size_t)BN * DN * 2);    // 64 KB
    uint32_t* min_all    = (uint32_t*)(meta + BN);                 // 16 KB
    uint32_t* min_larger = min_all + BN;                           // 16 KB
    uint32_t* done_count = min_larger + BN;                        // 4 B

    prep_kernel<<<BN / 4, 256, 0, stream>>>(anchor, positive, labels, Abf, meta,
                                            min_all, min_larger, done_count);
    gram_kernel<<<NBLK, 256, 0, stream>>>(Abf, meta, min_all, min_larger, done_count, out);
}

// Round 8
// 109.407 us; speedup vs baseline: 1.3977x; 1.3977x over previous
//
#include <hip/hip_runtime.h>
#include <hip/hip_bf16.h>
#include <cstdint>
#include <cstddef>

// Problem constants (fixed by the reference: anchor/positive [4096,512] f32, labels [4096] i32)
constexpr int BN = 4096;   // batch
constexpr int DN = 512;    // feature dim
constexpr int NT = BN / 128;              // 32 tiles per dim
constexpr int NBLK = NT * (NT + 1) / 2;   // 528 triangular tile-pairs
constexpr float MARGIN = 0.2f;
constexpr uint32_t INF_U = 0x7f800000u;   // +inf bits; positive-float order == uint order

typedef __attribute__((ext_vector_type(8))) short short8;     // 8 bf16 = 4 VGPRs (MFMA A/B frag)
typedef __attribute__((ext_vector_type(4))) float float4v;    // MFMA C/D frag

// ---------------------------------------------------------------------------
// Kernel 1: per-row stats + bf16 cast of anchor + init of min arrays + counter.
// One wave per row (4 rows / 256-thread block). Lane l owns elems [8l, 8l+8).
// meta[row] = {||a||^2, d_ap(squared), d_ap^2, label-bits}  (one b128 load later)
// ---------------------------------------------------------------------------
__global__ __launch_bounds__(256) void prep_kernel(
    const float* __restrict__ anchor,
    const float* __restrict__ positive,
    const int* __restrict__ labels,
    uint16_t* __restrict__ Abf,        // [BN][DN] bf16 bits
    float4* __restrict__ meta,         // [BN]
    uint32_t* __restrict__ min_all,    // [BN] +inf-initialized (min over d2)
    uint32_t* __restrict__ min_larger, // [BN] +inf-initialized (min over d2)
    uint32_t* __restrict__ done_count) // single counter, zeroed here
{
    const int tid  = threadIdx.x;
    const int wave = tid >> 6;
    const int lane = tid & 63;
    const int row  = blockIdx.x * 4 + wave;

    if (blockIdx.x == 0 && tid == 0) *done_count = 0;

    const float4* arow = (const float4*)(anchor   + (size_t)row * DN);
    const float4* prow = (const float4*)(positive + (size_t)row * DN);

    float4 av0 = arow[lane * 2 + 0], av1 = arow[lane * 2 + 1];
    float4 pv0 = prow[lane * 2 + 0], pv1 = prow[lane * 2 + 1];

    float a[8] = {av0.x, av0.y, av0.z, av0.w, av1.x, av1.y, av1.z, av1.w};
    float p[8] = {pv0.x, pv0.y, pv0.z, pv0.w, pv1.x, pv1.y, pv1.z, pv1.w};

    float s = 0.f, d = 0.f;
    union { uint16_t u[8]; uint4 v; } pk;
    #pragma unroll
    for (int i = 0; i < 8; ++i) {
        s += a[i] * a[i];
        float dx = a[i] - p[i];
        d += dx * dx;
        uint32_t ub = __float_as_uint(a[i]);               // RNE f32 -> bf16
        pk.u[i] = (uint16_t)((ub + 0x7fffu + ((ub >> 16) & 1u)) >> 16);
    }

    ((uint4*)(Abf + (size_t)row * DN))[lane] = pk.v;       // 16B coalesced store

    #pragma unroll
    for (int off = 32; off; off >>= 1) {
        s += __shfl_xor(s, off);
        d += __shfl_xor(d, off);
    }
    if (lane == 0) {
        meta[row] = (float4){s, d, d * d, __uint_as_float((uint32_t)labels[row])};
        min_all[row]    = INF_U;
        min_larger[row] = INF_U;
    }
}

// ---------------------------------------------------------------------------
// Kernel 2: upper-triangular 128x128 tiles of S = A·A^T (bf16 MFMA 16x16x32).
// BK=32, 16 fully-unrolled K-iters, SPILL-PROOF register pipeline: staging is
// 4 NAMED uint4 scalars (qa0,qa1,qb0,qb1 — SSA values, no arrays/lambda; R2 &
// R7 proved uint4[4] arrays live-across-barriers fail SROA and go to scratch:
// WRITE_SIZE 96/104 MB, VGPR_Count 72 = allocator never even used the regs).
// Per iter: [barrier -> 4 ds_write -> barrier -> issue 4 loads kt+1 ->
// 8 ds_read + 16 MFMA]; loads land during compute+barrier. Addressing: 4 base
// pointers + constant imm offsets (kt*64 B <= 960 < 4096). LDS 2x8 KB,
// XOR-4 swizzle (slot = chunk ^ row&3): write & frag-read phases each cover
// all 8 b128 slots -> conflict-free. Reg demand ~90 arch + 64 acc < 170 cap
// at launch_bounds(256,3). TRIPWIRE: WRITE_SIZE must stay ~5 MB.
// [R6: BK=128 -> 2 blocks/CU tail, regressed. R5: frag-from-global gathers,
// regressed. R1/R3: global_load_lds chain serialized at ~2.2k cyc/instr.]
// Epilogue: squared-distance dual-side masked mins via uint atomicMin.
// Last block (device counter) folds in the finalize: select, sqrt, hinge, mean.
// ---------------------------------------------------------------------------
__global__ __launch_bounds__(256, 3) void gram_kernel(
    const uint16_t* __restrict__ Abf,
    const float4* __restrict__ meta,
    uint32_t* __restrict__ min_all,
    uint32_t* __restrict__ min_larger,
    uint32_t* __restrict__ done_count,
    float* __restrict__ out)
{
    __shared__ uint16_t Abuf[128 * 32];   // 8 KB, row stride 32 elem = 64 B
    __shared__ uint16_t Bbuf[128 * 32];   // 8 KB

    // triangular decode: blockIdx.x -> (bi, bj) with bi <= bj
    int t = blockIdx.x, bi = 0, rem = NT;
    while (t >= rem) { t -= rem; ++bi; --rem; }
    const int bj = bi + t;
    const bool offdiag = (bi != bj);
    const int rowBase = bi * 128;
    const int colBase = bj * 128;

    const int tid  = threadIdx.x;
    const int lane = tid & 63;
    const int wave = tid >> 6;
    const int wi   = wave >> 1;       // wave row in 2x2 grid
    const int wj   = wave & 1;        // wave col
    const int quad = lane >> 4;
    const int l15  = lane & 15;

    // Staging map: tile = 128 rows x 4 chunks of 16B = 512 chunks; thread
    // handles chunks c0=tid, c1=tid+256. row=c>>2, chunk=c&3,
    // LDS slot = chunk ^ (row&3)  (XOR-4 swizzle).
    const int sr0 = tid >> 2,         sc0 = tid & 3,  sp0 = sc0 ^ (sr0 & 3);
    const int sr1 = (tid + 256) >> 2, sc1 = sc0,      sp1 = sc0 ^ (sr1 & 3);

    const uint16_t* pa0 = Abf + (size_t)(rowBase + sr0) * DN + sc0 * 8;
    const uint16_t* pa1 = Abf + (size_t)(rowBase + sr1) * DN + sc1 * 8;
    const uint16_t* pb0 = Abf + (size_t)(colBase + sr0) * DN + sc0 * 8;
    const uint16_t* pb1 = Abf + (size_t)(colBase + sr1) * DN + sc1 * 8;

    uint16_t* const wa0 = Abuf + sr0 * 32 + sp0 * 8;
    uint16_t* const wa1 = Abuf + sr1 * 32 + sp1 * 8;
    uint16_t* const wb0 = Bbuf + sr0 * 32 + sp0 * 8;
    uint16_t* const wb1 = Bbuf + sr1 * 32 + sp1 * 8;

    // Frag read bases: row r = w*64 + mi*16 + l15, slot = quad ^ (l15&3)
    const int fp = quad ^ (l15 & 3);
    const uint16_t* const ra = Abuf + (wi * 64 + l15) * 32 + fp * 8;
    const uint16_t* const rb = Bbuf + (wj * 64 + l15) * 32 + fp * 8;

    // Named-scalar staging registers (16 VGPRs) — prologue load of tile 0.
    uint4 qa0 = *(const uint4*)pa0;
    uint4 qa1 = *(const uint4*)pa1;
    uint4 qb0 = *(const uint4*)pb0;
    uint4 qb1 = *(const uint4*)pb1;

    float4v acc[4][4];
    #pragma unroll
    for (int i = 0; i < 4; ++i)
        #pragma unroll
        for (int j = 0; j < 4; ++j)
            acc[i][j] = (float4v){0.f, 0.f, 0.f, 0.f};

    #pragma unroll
    for (int kt = 0; kt < DN / 32; ++kt) {
        __syncthreads();              // readers of previous tile done
        *(uint4*)wa0 = qa0;
        *(uint4*)wa1 = qa1;
        *(uint4*)wb0 = qb0;
        *(uint4*)wb1 = qb1;
        __syncthreads();              // LDS tile visible
        if (kt < DN / 32 - 1) {       // issue next tile's loads; land during MFMA
            qa0 = *(const uint4*)(pa0 + (kt + 1) * 32);
            qa1 = *(const uint4*)(pa1 + (kt + 1) * 32);
            qb0 = *(const uint4*)(pb0 + (kt + 1) * 32);
            qb1 = *(const uint4*)(pb1 + (kt + 1) * 32);
        }
        short8 af[4], bfr[4];
        #pragma unroll
        for (int mi = 0; mi < 4; ++mi)
            af[mi] = *(const short8*)(ra + mi * 16 * 32);
        #pragma unroll
        for (int mj = 0; mj < 4; ++mj)
            bfr[mj] = *(const short8*)(rb + mj * 16 * 32);
        #pragma unroll
        for (int mi = 0; mi < 4; ++mi)
            #pragma unroll
            for (int mj = 0; mj < 4; ++mj)
                acc[mi][mj] = __builtin_amdgcn_mfma_f32_16x16x32_bf16(
                    af[mi], bfr[mj], acc[mi][mj], 0, 0, 0);
    }

    // ---- epilogue: squared distances, dual-side masked mins ----
    const float INFF = __uint_as_float(INF_U);
    float4 mj_meta[4];
    #pragma unroll
    for (int mj = 0; mj < 4; ++mj)
        mj_meta[mj] = meta[colBase + wj * 64 + mj * 16 + l15];   // C/D col = lane&15

    float cAll[4], cLarger[4];
    #pragma unroll
    for (int mj = 0; mj < 4; ++mj) { cAll[mj] = INFF; cLarger[mj] = INFF; }

    #pragma unroll
    for (int mi = 0; mi < 4; ++mi) {
        #pragma unroll
        for (int r = 0; r < 4; ++r) {
            int row = rowBase + wi * 64 + mi * 16 + quad * 4 + r;  // C/D row = quad*4+reg
            float4 mim = meta[row];          // {sqn, dap, dap^2, label}
            uint32_t li = __float_as_uint(mim.w);
            float mAll = INFF, mLarger = INFF;
            #pragma unroll
            for (int mj = 0; mj < 4; ++mj) {
                float d2 = mim.x + mj_meta[mj].x - 2.0f * acc[mi][mj][r];
                d2 = d2 > 0.f ? d2 : 0.f;
                if (__float_as_uint(mj_meta[mj].w) != li) {
                    mAll = fminf(mAll, d2);
                    // reference: pd (euclidean) > d_ap (squared)  <=>  d2 > dap^2
                    if (d2 > mim.z) mLarger = fminf(mLarger, d2);
                    if (offdiag) {
                        cAll[mj] = fminf(cAll[mj], d2);
                        if (d2 > mj_meta[mj].z) cLarger[mj] = fminf(cLarger[mj], d2);
                    }
                }
            }
            // min across the 16 lanes of this quad (they share `row`, cover 64 cols)
            #pragma unroll
            for (int off = 1; off < 16; off <<= 1) {
                mAll    = fminf(mAll,    __shfl_xor(mAll, off));
                mLarger = fminf(mLarger, __shfl_xor(mLarger, off));
            }
            if (l15 == 0) {
                atomicMin(&min_all[row],    __float_as_uint(mAll));
                atomicMin(&min_larger[row], __float_as_uint(mLarger));
            }
        }
    }
    if (offdiag) {
        // col j = colBase + wj*64 + mj*16 + l15 is shared by the 4 quads
        #pragma unroll
        for (int mj = 0; mj < 4; ++mj) {
            float a0 = cAll[mj], l0 = cLarger[mj];
            a0 = fminf(a0, __shfl_xor(a0, 16)); l0 = fminf(l0, __shfl_xor(l0, 16));
            a0 = fminf(a0, __shfl_xor(a0, 32)); l0 = fminf(l0, __shfl_xor(l0, 32));
            if (quad == 0) {
                int col = colBase + wj * 64 + mj * 16 + l15;
                atomicMin(&min_all[col],    __float_as_uint(a0));
                atomicMin(&min_larger[col], __float_as_uint(l0));
            }
        }
    }

    // ---- last-block finalize: select, sqrt, hinge, mean ----
    __shared__ bool isLast;
    __syncthreads();                      // all this block's atomics issued
    if (tid == 0) {
        __threadfence();                  // make our mins visible device-wide
        isLast = (atomicAdd(done_count, 1u) == NBLK - 1);
    }
    __syncthreads();
    if (isLast) {
        __threadfence();                  // acquire: see all other blocks' mins
        float s = 0.f;
        for (int i = tid; i < BN; i += 256) {
            uint32_t mlu = __hip_atomic_load(&min_larger[i], __ATOMIC_RELAXED, __HIP_MEMORY_SCOPE_AGENT);
            uint32_t mau = __hip_atomic_load(&min_all[i],    __ATOMIC_RELAXED, __HIP_MEMORY_SCOPE_AGENT);
            float dan2 = (mlu != INF_U) ? __uint_as_float(mlu) : __uint_as_float(mau);
            float l = meta[i].y - sqrtf(dan2) + MARGIN;
            s += l > 0.f ? l : 0.f;
        }
        #pragma unroll
        for (int off = 32; off; off >>= 1) s += __shfl_xor(s, off);
        __shared__ float wsum[4];
        if ((tid & 63) == 0) wsum[tid >> 6] = s;
        __syncthreads();
        if (tid == 0) out[0] = (wsum[0] + wsum[1] + wsum[2] + wsum[3]) * (1.0f / BN);
    }
}

// ---------------------------------------------------------------------------
extern "C" void kernel_launch(void* const* d_in, const int* in_sizes, int n_in,
                              void* d_out, int out_size, void* d_ws, size_t ws_size,
                              hipStream_t stream) {
    const float* anchor   = (const float*)d_in[0];
    const float* positive = (const float*)d_in[1];
    const int*   labels   = (const int*)d_in[2];
    float* out = (float*)d_out;

    // Workspace layout (~4.4 MB)
    uint8_t* ws = (uint8_t*)d_ws;
    uint16_t* Abf        = (uint16_t*)ws;                          // 4 MB bf16 anchor
    float4*   meta       = (float4*)(ws + (size_t)BN * DN * 2);    // 64 KB
    uint32_t* min_all    = (uint32_t*)(meta + BN);                 // 16 KB
    uint32_t* min_larger = min_all + BN;                           // 16 KB
    uint32_t* done_count = min_larger + BN;                        // 4 B

    prep_kernel<<<BN / 4, 256, 0, stream>>>(anchor, positive, labels, Abf, meta,
                                            min_all, min_larger, done_count);
    gram_kernel<<<NBLK, 256, 0, stream>>>(Abf, meta, min_all, min_larger, done_count, out);
}